// Round 7
// baseline (288.509 us; speedup 1.0000x reference)
//
#include <hip/hip_runtime.h>
#include <stdint.h>

#define NSAMP 1024
#define D 16384
#define WH 128
#define MARGIN 0.3f
#define NTILES 36
#define SCALE 0.08838834764831845f    // 1/sqrt(128)
#define RSCALE 11.313708498984761f    // sqrt(128)

typedef unsigned int uint;
typedef unsigned short ushort_t;

typedef __attribute__((ext_vector_type(8))) short bf16x8;   // 8 bf16 = 4 VGPRs
typedef __attribute__((ext_vector_type(4))) float f32x4;

__device__ __forceinline__ float bf2f(unsigned short b) {
    return __uint_as_float(((uint)b) << 16);
}
__device__ __forceinline__ unsigned short f2bf(float f) {
    uint u = __float_as_uint(f);
    u += 0x7fffu + ((u >> 16) & 1u);   // RNE (data has no NaN)
    return (unsigned short)(u >> 16);
}
__device__ __forceinline__ void gload_lds16(const void* g, void* l) {
    __builtin_amdgcn_global_load_lds(
        (const __attribute__((address_space(1))) uint32_t*)g,
        (__attribute__((address_space(3))) uint32_t*)l, 16, 0, 0);
}
// Halve all 8 bf16 lanes: exponent-field decrement (exact; hi-split of N(0,1)
// data is never subnormal/zero, so no borrow).
__device__ __forceinline__ bf16x8 bf8_half(bf16x8 v) {
    union { bf16x8 b; uint u[4]; } c;
    c.b = v;
    c.u[0] -= 0x00800080u; c.u[1] -= 0x00800080u;
    c.u[2] -= 0x00800080u; c.u[3] -= 0x00800080u;
    return c.b;
}
// Swizzled LDS byte offset for a 128-col bf16 row-major tile.
__device__ __forceinline__ int lds_off(int row, int col) {
    return row * 256 + ((((col >> 3) ^ (row & 15)) << 4) | ((col & 7) << 1));
}

// ---------------- kernel 1: row norms + hi/lo bf16 split ----------------
__global__ __launch_bounds__(256) void k_norms_split(const float* __restrict__ x,
                                                     float* __restrict__ sq,
                                                     ushort_t* __restrict__ xhi,
                                                     ushort_t* __restrict__ xlo) {
    int b = blockIdx.x;
    int tid = threadIdx.x;
    const float* xr = x + (size_t)b * D;
    ushort_t* hr = xhi + (size_t)b * D;
    ushort_t* lr = xlo + (size_t)b * D;
    float s = 0.f;
    #pragma unroll
    for (int m = 0; m < 16; ++m) {
        int e = m * 1024 + tid * 4;
        float4 v = *(const float4*)(xr + e);
        s += v.x * v.x + v.y * v.y + v.z * v.z + v.w * v.w;
        ushort4 h, l;
        h.x = f2bf(v.x); l.x = f2bf(v.x - bf2f(h.x));
        h.y = f2bf(v.y); l.y = f2bf(v.y - bf2f(h.y));
        h.z = f2bf(v.z); l.z = f2bf(v.z - bf2f(h.z));
        h.w = f2bf(v.w); l.w = f2bf(v.w - bf2f(h.w));
        *(ushort4*)(hr + e) = h;
        *(ushort4*)(lr + e) = l;
    }
    for (int off = 32; off; off >>= 1) s += __shfl_down(s, off, 64);
    __shared__ float red[4];
    if ((tid & 63) == 0) red[tid >> 6] = s;
    __syncthreads();
    if (tid == 0) sq[b] = red[0] + red[1] + red[2] + red[3];
}

// ---------------- kernel 2: lower-triangle Gram partials via MFMA ----------
// Tile t covers (bi,bj), bi>=bj. Off-diagonal: full G = HH + HL^T + LH^T
// (3 chains). Diagonal: GB = 0.5*HH + HL^T (2 chains); fold adds GB+GB^T.
// Tile-compact storage: Gp[((ks*36)+t)*16384 + r*128 + c].
// ks in low bits of lin -> XCD-pinned K-slices (R5: FETCH 150->42 MB).
__global__ __launch_bounds__(256) void k_gram_tri(const ushort_t* __restrict__ xhi,
                                                  const ushort_t* __restrict__ xlo,
                                                  float* __restrict__ Gp,
                                                  int ksmask, int ksshift, int ksub) {
    int lin = blockIdx.x;
    int ks = lin & ksmask;
    int t = lin >> ksshift;
    int bi = 0;
    while (t >= ((bi + 1) * (bi + 2)) / 2) ++bi;
    int bj = t - (bi * (bi + 1)) / 2;
    bool diag = (bi == bj);
    int i0 = bi * 128, j0 = bj * 128;
    int tid = threadIdx.x;
    int w = tid >> 6, lane = tid & 63;
    int wm = w & 1, wn = w >> 1;
    int quad = lane >> 4, m16 = lane & 15;
    int srow = lane >> 2, sseg = lane & 3;

    __shared__ __align__(16) ushort_t Ahi_s[128 * 32];
    __shared__ __align__(16) ushort_t Alo_s[128 * 32];
    __shared__ __align__(16) ushort_t Bhi_s[128 * 32];
    __shared__ __align__(16) ushort_t Blo_s[128 * 32];

    f32x4 acc[4][4];
    #pragma unroll
    for (int ii = 0; ii < 4; ++ii)
        #pragma unroll
        for (int jj = 0; jj < 4; ++jj)
            acc[ii][jj] = (f32x4){0.f, 0.f, 0.f, 0.f};

    const size_t Abase = (size_t)i0 * D;
    const size_t Bbase = (size_t)j0 * D;

    for (int kb = 0; kb < ksub / 32; ++kb) {
        int k0 = ks * ksub + kb * 32;
        #pragma unroll
        for (int c = 0; c < 2; ++c) {
            int r = w * 32 + c * 16 + srow;
            size_t go = (size_t)r * D + k0 + sseg * 8;
            int lo = (w * 32 + c * 16) * 32;
            gload_lds16(xhi + Abase + go, &Ahi_s[lo]);
            gload_lds16(xlo + Bbase + go, &Blo_s[lo]);
            if (!diag) {
                gload_lds16(xhi + Bbase + go, &Bhi_s[lo]);
                gload_lds16(xlo + Abase + go, &Alo_s[lo]);
            }
        }
        __syncthreads();

        bf16x8 ah[4], bh[4], bl[4];
        #pragma unroll
        for (int ii = 0; ii < 4; ++ii) {
            int ar = wm * 64 + ii * 16 + m16;
            ah[ii] = *(const bf16x8*)&Ahi_s[ar * 32 + quad * 8];
        }
        const ushort_t* Bh = diag ? Ahi_s : Bhi_s;
        #pragma unroll
        for (int jj = 0; jj < 4; ++jj) {
            int br = wn * 64 + jj * 16 + m16;
            bh[jj] = *(const bf16x8*)&Bh[br * 32 + quad * 8];
            bl[jj] = *(const bf16x8*)&Blo_s[br * 32 + quad * 8];
        }
        if (diag) {
            #pragma unroll
            for (int ii = 0; ii < 4; ++ii) {
                bf16x8 ahh = bf8_half(ah[ii]);
                #pragma unroll
                for (int jj = 0; jj < 4; ++jj) {
                    acc[ii][jj] = __builtin_amdgcn_mfma_f32_16x16x32_bf16(ahh, bh[jj], acc[ii][jj], 0, 0, 0);
                    acc[ii][jj] = __builtin_amdgcn_mfma_f32_16x16x32_bf16(ah[ii], bl[jj], acc[ii][jj], 0, 0, 0);
                }
            }
        } else {
            bf16x8 al[4];
            #pragma unroll
            for (int ii = 0; ii < 4; ++ii) {
                int ar = wm * 64 + ii * 16 + m16;
                al[ii] = *(const bf16x8*)&Alo_s[ar * 32 + quad * 8];
            }
            #pragma unroll
            for (int ii = 0; ii < 4; ++ii)
                #pragma unroll
                for (int jj = 0; jj < 4; ++jj) {
                    acc[ii][jj] = __builtin_amdgcn_mfma_f32_16x16x32_bf16(ah[ii], bh[jj], acc[ii][jj], 0, 0, 0);
                    acc[ii][jj] = __builtin_amdgcn_mfma_f32_16x16x32_bf16(ah[ii], bl[jj], acc[ii][jj], 0, 0, 0);
                    acc[ii][jj] = __builtin_amdgcn_mfma_f32_16x16x32_bf16(al[ii], bh[jj], acc[ii][jj], 0, 0, 0);
                }
        }
        __syncthreads();
    }

    float* Gb = Gp + ((size_t)ks * NTILES + t) * 16384;
    #pragma unroll
    for (int ii = 0; ii < 4; ++ii)
        #pragma unroll
        for (int jj = 0; jj < 4; ++jj) {
            int rg = wm * 64 + ii * 16 + quad * 4;
            int cg = wn * 64 + jj * 16 + m16;
            #pragma unroll
            for (int r = 0; r < 4; ++r)
                Gb[(size_t)(rg + r) * 128 + cg] = acc[ii][jj][r];
        }
}

// ---------------- kernel 2b: fold partials + mirror to full G ----------------
// grid (16,16); output 64x64 tile at rows I*64, cols J*64.
//   bi>bj : direct sum of stored tile (bi,bj)
//   bi<bj : transpose of stored tile (bj,bi)      (LDS transpose)
//   bi==bj: direct + transpose of same tile (GB + GB^T)
__global__ __launch_bounds__(256) void k_fold_tri(const float* __restrict__ Gp,
                                                  float* __restrict__ G, int nks) {
    int J = blockIdx.x, I = blockIdx.y;
    int bi = I >> 1, bj = J >> 1;
    int li = I & 1, lj = J & 1;
    bool wantD = (bi >= bj);
    bool wantT = (bi <= bj);
    int tD = wantD ? (bi * (bi + 1)) / 2 + bj : 0;
    int tT = wantT ? (bj * (bj + 1)) / 2 + bi : 0;

    int t = threadIdx.x;
    int r = t >> 4, c4 = (t & 15) * 4;
    __shared__ float TJ[64][65];
    float4 sIJ[4];
    #pragma unroll
    for (int rr = 0; rr < 4; ++rr) {
        int row = rr * 16 + r;
        float4 a = {0.f, 0.f, 0.f, 0.f}, bb = {0.f, 0.f, 0.f, 0.f};
        if (wantD) {
            size_t off = (size_t)(li * 64 + row) * 128 + lj * 64 + c4;
            #pragma unroll 4
            for (int p = 0; p < nks; ++p) {
                float4 v = *(const float4*)(Gp + ((size_t)p * NTILES + tD) * 16384 + off);
                a.x += v.x; a.y += v.y; a.z += v.z; a.w += v.w;
            }
        }
        if (wantT) {
            size_t off = (size_t)(lj * 64 + row) * 128 + li * 64 + c4;
            #pragma unroll 4
            for (int p = 0; p < nks; ++p) {
                float4 v = *(const float4*)(Gp + ((size_t)p * NTILES + tT) * 16384 + off);
                bb.x += v.x; bb.y += v.y; bb.z += v.z; bb.w += v.w;
            }
        }
        sIJ[rr] = a;
        TJ[row][c4 + 0] = bb.x; TJ[row][c4 + 1] = bb.y;
        TJ[row][c4 + 2] = bb.z; TJ[row][c4 + 3] = bb.w;
    }
    __syncthreads();
    #pragma unroll
    for (int rr = 0; rr < 4; ++rr) {
        int row = rr * 16 + r;
        float4 v = sIJ[rr];
        if (wantT) {
            v.x += TJ[c4 + 0][row]; v.y += TJ[c4 + 1][row];
            v.z += TJ[c4 + 2][row]; v.w += TJ[c4 + 3][row];
        }
        *(float4*)(G + (size_t)(I * 64 + row) * NSAMP + J * 64 + c4) = v;
    }
}

// ---------------- kernel 3: hardest pos/neg (row reads only) ----------------
__global__ void k_select(const float* __restrict__ G,
                         const float* __restrict__ sq, const int* __restrict__ tgt,
                         int* __restrict__ hp, int* __restrict__ hn) {
    int i = blockIdx.x;
    int tid = threadIdx.x;
    float sqi = sq[i];
    int ti = tgt[i];
    float pv = -3.0e38f; int pj = 0x7FFFFFFF;
    float nv = 3.0e38f;  int nj = 0x7FFFFFFF;
    #pragma unroll
    for (int m = 0; m < 4; ++m) {
        int j = tid + 256 * m;
        float g = G[(size_t)i * NSAMP + j];
        float d2 = sqi + sq[j] - 2.f * g;
        float d = sqrtf(fmaxf(d2, 1e-12f));
        bool same = (tgt[j] == ti);
        float cp = same ? d : -1e30f;
        float cn = same ? 1e30f : d;
        if (cp > pv || (cp == pv && j < pj)) { pv = cp; pj = j; }
        if (cn < nv || (cn == nv && j < nj)) { nv = cn; nj = j; }
    }
    for (int off = 32; off; off >>= 1) {
        float opv = __shfl_down(pv, off, 64); int opj = __shfl_down(pj, off, 64);
        float onv = __shfl_down(nv, off, 64); int onj = __shfl_down(nj, off, 64);
        if (opv > pv || (opv == pv && opj < pj)) { pv = opv; pj = opj; }
        if (onv < nv || (onv == nv && onj < nj)) { nv = onv; nj = onj; }
    }
    __shared__ float spv[4], snv[4];
    __shared__ int spj[4], snj[4];
    if ((tid & 63) == 0) { int wv = tid >> 6; spv[wv] = pv; spj[wv] = pj; snv[wv] = nv; snj[wv] = nj; }
    __syncthreads();
    if (tid == 0) {
        for (int wv = 1; wv < 4; ++wv) {
            if (spv[wv] > pv || (spv[wv] == pv && spj[wv] < pj)) { pv = spv[wv]; pj = spj[wv]; }
            if (snv[wv] < nv || (snv[wv] == nv && snj[wv] < nj)) { nv = snv[wv]; nj = snj[wv]; }
        }
        hp[i] = pj; hn[i] = nj;
    }
}

// ---------------- kernel 4: DC align via MFMA, pos+neg fused ----------------
// grid (b=1024), 4 waves. A-frags loaded once; O_pos then O_neg staged
// sequentially into the same 32KB LDS. dsq written exclusively (no atomics).
__global__ __launch_bounds__(256) void k_dc_mfma(const ushort_t* __restrict__ xhi,
                                                 const int* __restrict__ hp,
                                                 const int* __restrict__ hn,
                                                 const float* __restrict__ sq,
                                                 float* __restrict__ dsq) {
    int b = blockIdx.x;
    const ushort_t* Ag = xhi + (size_t)b * D;

    __shared__ __align__(16) char smem[32768];   // O, then Ot in place
    __shared__ float red2[2][4];

    int tid = threadIdx.x;
    int wv = tid >> 6, lane = tid & 63;
    int quad = lane >> 4, m16 = lane & 15;

    // A-frags from global (own rows per wave), reused for both which
    bf16x8 af[2][4];
    #pragma unroll
    for (int tj2 = 0; tj2 < 2; ++tj2) {
        int r = (2 * wv + tj2) * 16 + m16;
        #pragma unroll
        for (int ks = 0; ks < 4; ++ks)
            af[tj2][ks] = *(const bf16x8*)(Ag + r * WH + ks * 32 + quad * 8);
    }

    for (int which = 0; which < 2; ++which) {
        int oidx = (which == 0) ? hp[b] : hn[b];
        const ushort_t* Og = xhi + (size_t)oidx * D;

        // stage O into swizzled LDS
        uint4 stg[8];
        #pragma unroll
        for (int k = 0; k < 8; ++k)
            stg[k] = *(const uint4*)((const char*)Og + (size_t)(tid + 256 * k) * 16);
        if (which) __syncthreads();   // prior M-pass LDS reads complete
        #pragma unroll
        for (int k = 0; k < 8; ++k) {
            int g = tid + 256 * k;
            *(uint4*)(smem + lds_off(g >> 4, (g & 15) * 8)) = stg[k];
        }
        __syncthreads();   // B1: O staged

        // ---- S^T pass ----
        f32x4 accS[8][2];
        #pragma unroll
        for (int ti = 0; ti < 8; ++ti)
            #pragma unroll
            for (int tj2 = 0; tj2 < 2; ++tj2)
                accS[ti][tj2] = (f32x4){0.f, 0.f, 0.f, 0.f};
        #pragma unroll
        for (int ks = 0; ks < 4; ++ks) {
            bf16x8 of[8];
            #pragma unroll
            for (int ti = 0; ti < 8; ++ti)
                of[ti] = *(const bf16x8*)(smem + lds_off(ti * 16 + m16, (ks * 4 + quad) * 8));
            #pragma unroll
            for (int ti = 0; ti < 8; ++ti)
                #pragma unroll
                for (int tj2 = 0; tj2 < 2; ++tj2)
                    accS[ti][tj2] = __builtin_amdgcn_mfma_f32_16x16x32_bf16(of[ti], af[tj2][ks], accS[ti][tj2], 0, 0, 0);
        }

        // transpose read phase (O still valid)
        int c0 = (tid & 31) * 4, h0 = (tid >> 5) * 16;
        uint4 trd[4][2];
        #pragma unroll
        for (int j = 0; j < 4; ++j)
            #pragma unroll
            for (int k = 0; k < 2; ++k)
                trd[j][k] = *(const uint4*)(smem + lds_off(c0 + j, h0 + 8 * k));
        __syncthreads();   // B2: all O reads done

        // transpose write: (c,h) -> (h,c) in place
        #pragma unroll
        for (int i = 0; i < 16; ++i) {
            uint v[4];
            #pragma unroll
            for (int j = 0; j < 4; ++j) {
                uint wo = ((const uint*)&trd[j][i >> 3])[(i >> 1) & 3];
                v[j] = (i & 1) ? (wo >> 16) : (wo & 0xffffu);
            }
            uint2 pk;
            pk.x = v[0] | (v[1] << 16);
            pk.y = v[2] | (v[3] << 16);
            *(uint2*)(smem + lds_off(h0 + i, c0)) = pk;
        }

        // ---- softmax over c + in-register P-frag build ----
        float tpart = 0.f;
        bf16x8 pf[2][4];
        #pragma unroll
        for (int tj2 = 0; tj2 < 2; ++tj2) {
            float mx = -3.0e38f;
            #pragma unroll
            for (int ti = 0; ti < 8; ++ti)
                #pragma unroll
                for (int r = 0; r < 4; ++r) {
                    float s = accS[ti][tj2][r] * SCALE;
                    accS[ti][tj2][r] = s;
                    mx = fmaxf(mx, s);
                }
            mx = fmaxf(mx, __shfl_xor(mx, 16, 64));
            mx = fmaxf(mx, __shfl_xor(mx, 32, 64));
            float sum = 0.f, tnum = 0.f;
            #pragma unroll
            for (int ti = 0; ti < 8; ++ti)
                #pragma unroll
                for (int r = 0; r < 4; ++r) {
                    float s = accS[ti][tj2][r];
                    float e = __expf(s - mx);
                    accS[ti][tj2][r] = e;
                    sum += e;
                    tnum += s * e;
                }
            sum += __shfl_xor(sum, 16, 64);
            sum += __shfl_xor(sum, 32, 64);
            tnum += __shfl_xor(tnum, 16, 64);
            tnum += __shfl_xor(tnum, 32, 64);
            float inv = 1.f / sum;
            tpart += 0.25f * tnum * inv;

            uint Ep[8][2];
            #pragma unroll
            for (int ti = 0; ti < 8; ++ti) {
                Ep[ti][0] = (uint)f2bf(accS[ti][tj2][0] * inv) |
                            ((uint)f2bf(accS[ti][tj2][1] * inv) << 16);
                Ep[ti][1] = (uint)f2bf(accS[ti][tj2][2] * inv) |
                            ((uint)f2bf(accS[ti][tj2][3] * inv) << 16);
            }
            int tih = quad >> 1;
            #pragma unroll
            for (int ks = 0; ks < 4; ++ks) {
                union { uint u[4]; bf16x8 v; } fr;
                #pragma unroll
                for (int k = 0; k < 4; ++k) {
                    int src = (((quad << 1) + (k >> 1)) & 3) * 16 + m16;
                    int a = __shfl((int)Ep[2 * ks + 0][k & 1], src, 64);
                    int bsh = __shfl((int)Ep[2 * ks + 1][k & 1], src, 64);
                    fr.u[k] = (uint)((tih == 0) ? a : bsh);
                }
                pf[tj2][ks] = fr.v;
            }
        }
        __syncthreads();   // B3: Ot complete

        // ---- M pass ----
        f32x4 accM[2][8];
        #pragma unroll
        for (int tj2 = 0; tj2 < 2; ++tj2)
            #pragma unroll
            for (int tj = 0; tj < 8; ++tj)
                accM[tj2][tj] = (f32x4){0.f, 0.f, 0.f, 0.f};
        #pragma unroll
        for (int ks = 0; ks < 4; ++ks) {
            bf16x8 otf[8];
            #pragma unroll
            for (int tj = 0; tj < 8; ++tj)
                otf[tj] = *(const bf16x8*)(smem + lds_off(tj * 16 + m16, (ks * 4 + quad) * 8));
            #pragma unroll
            for (int tj2 = 0; tj2 < 2; ++tj2)
                #pragma unroll
                for (int tj = 0; tj < 8; ++tj)
                    accM[tj2][tj] = __builtin_amdgcn_mfma_f32_16x16x32_bf16(pf[tj2][ks], otf[tj], accM[tj2][tj], 0, 0, 0);
        }

        float m2 = 0.f;
        #pragma unroll
        for (int tj2 = 0; tj2 < 2; ++tj2)
            #pragma unroll
            for (int tj = 0; tj < 8; ++tj)
                #pragma unroll
                for (int r = 0; r < 4; ++r) {
                    float mvv = accM[tj2][tj][r];
                    m2 += mvv * mvv;
                }
        float part = m2 - 2.f * RSCALE * tpart;
        for (int off = 32; off; off >>= 1) part += __shfl_down(part, off, 64);
        if (lane == 0) red2[which][wv] = part;
    }
    __syncthreads();
    if (tid < 2) {
        float p = red2[tid][0] + red2[tid][1] + red2[tid][2] + red2[tid][3];
        dsq[tid * NSAMP + b] = sq[b] + p;
    }
}

// ---------------- kernel 5: final loss ----------------
__global__ void k_loss(const float* __restrict__ dsq, float* __restrict__ out) {
    int tid = threadIdx.x;
    float s = 0.f;
    #pragma unroll
    for (int m = 0; m < 4; ++m) {
        int b = tid + 256 * m;
        float ap = sqrtf(fmaxf(dsq[b], 0.f));
        float an = sqrtf(fmaxf(dsq[NSAMP + b], 0.f));
        s += fmaxf(ap - an + MARGIN, 0.f);
    }
    for (int off = 32; off; off >>= 1) s += __shfl_down(s, off, 64);
    __shared__ float red[4];
    if ((tid & 63) == 0) red[tid >> 6] = s;
    __syncthreads();
    if (tid == 0) out[0] = (red[0] + red[1] + red[2] + red[3]) * (1.f / NSAMP);
}

extern "C" void kernel_launch(void* const* d_in, const int* in_sizes, int n_in,
                              void* d_out, int out_size, void* d_ws, size_t ws_size,
                              hipStream_t stream) {
    const float* x = (const float*)d_in[0];
    const int* tgt = (const int*)d_in[1];
    float* out = (float*)d_out;
    char* ws = (char*)d_ws;

    // KS=16 needs Gp 36MB + xhi 32MB + xlo 32MB + tail; fall back to KS=8.
    const size_t XB = (size_t)NSAMP * D * 2;          // 32 MB per bf16 matrix
    size_t gp16 = (size_t)16 * NTILES * 16384 * 4;    // 36 MB
    size_t gp8 = (size_t)8 * NTILES * 16384 * 4;      // 18 MB
    int nks = (ws_size >= gp16 + 2 * XB + (size_t)65536) ? 16 : 8;
    size_t gpb = (nks == 16) ? gp16 : gp8;

    float* Gp = (float*)ws;
    ushort_t* xhi = (ushort_t*)(ws + gpb);
    ushort_t* xlo = (ushort_t*)(ws + gpb + XB);
    float* G = (float*)xlo;                            // 4 MB, xlo dead after gram
    float* sq = (float*)(ws + gpb + 2 * XB);
    float* dsq = sq + NSAMP;
    int* hp = (int*)(dsq + 2 * NSAMP);
    int* hn = hp + NSAMP;

    k_norms_split<<<NSAMP, 256, 0, stream>>>(x, sq, xhi, xlo);
    k_gram_tri<<<NTILES * nks, 256, 0, stream>>>(xhi, xlo, Gp, nks - 1,
                                                 (nks == 16) ? 4 : 3, D / nks);
    k_fold_tri<<<dim3(16, 16), 256, 0, stream>>>(Gp, G, nks);
    k_select<<<NSAMP, 256, 0, stream>>>(G, sq, tgt, hp, hn);
    k_dc_mfma<<<NSAMP, 256, 0, stream>>>(xhi, hp, hn, sq, dsq);
    k_loss<<<1, 256, 0, stream>>>(dsq, out);
}

// Round 8
// 251.077 us; speedup vs baseline: 1.1491x; 1.1491x over previous
//
#include <hip/hip_runtime.h>
#include <stdint.h>

#define NSAMP 1024
#define D 16384
#define WH 128
#define MARGIN 0.3f
#define KS 8
#define KSUB (D / KS)
#define SCALE 0.08838834764831845f    // 1/sqrt(128)
#define RSCALE 11.313708498984761f    // sqrt(128)

typedef unsigned int uint;
typedef unsigned short ushort_t;

typedef __attribute__((ext_vector_type(8))) short bf16x8;   // 8 bf16 = 4 VGPRs
typedef __attribute__((ext_vector_type(4))) float f32x4;

__device__ __forceinline__ float bf2f(unsigned short b) {
    return __uint_as_float(((uint)b) << 16);
}
__device__ __forceinline__ unsigned short f2bf(float f) {
    uint u = __float_as_uint(f);
    u += 0x7fffu + ((u >> 16) & 1u);   // RNE (data has no NaN)
    return (unsigned short)(u >> 16);
}
__device__ __forceinline__ void gload_lds16(const void* g, void* l) {
    __builtin_amdgcn_global_load_lds(
        (const __attribute__((address_space(1))) uint32_t*)g,
        (__attribute__((address_space(3))) uint32_t*)l, 16, 0, 0);
}
// Halve all 8 bf16 lanes: exponent-field decrement (exact; hi-split of N(0,1)
// data is never subnormal/zero, so no borrow).
__device__ __forceinline__ bf16x8 bf8_half(bf16x8 v) {
    union { bf16x8 b; uint u[4]; } c;
    c.b = v;
    c.u[0] -= 0x00800080u; c.u[1] -= 0x00800080u;
    c.u[2] -= 0x00800080u; c.u[3] -= 0x00800080u;
    return c.b;
}
// Swizzled LDS byte offset for a 128-col bf16 row-major tile.
__device__ __forceinline__ int lds_off(int row, int col) {
    return row * 256 + ((((col >> 3) ^ (row & 15)) << 4) | ((col & 7) << 1));
}

// ---------------- kernel 1: row norms + hi/lo bf16 split ----------------
__global__ __launch_bounds__(256) void k_norms_split(const float* __restrict__ x,
                                                     float* __restrict__ sq,
                                                     ushort_t* __restrict__ xhi,
                                                     ushort_t* __restrict__ xlo) {
    int b = blockIdx.x;
    int tid = threadIdx.x;
    const float* xr = x + (size_t)b * D;
    ushort_t* hr = xhi + (size_t)b * D;
    ushort_t* lr = xlo + (size_t)b * D;
    float s = 0.f;
    #pragma unroll
    for (int m = 0; m < 16; ++m) {
        int e = m * 1024 + tid * 4;
        float4 v = *(const float4*)(xr + e);
        s += v.x * v.x + v.y * v.y + v.z * v.z + v.w * v.w;
        ushort4 h, l;
        h.x = f2bf(v.x); l.x = f2bf(v.x - bf2f(h.x));
        h.y = f2bf(v.y); l.y = f2bf(v.y - bf2f(h.y));
        h.z = f2bf(v.z); l.z = f2bf(v.z - bf2f(h.z));
        h.w = f2bf(v.w); l.w = f2bf(v.w - bf2f(h.w));
        *(ushort4*)(hr + e) = h;
        *(ushort4*)(lr + e) = l;
    }
    for (int off = 32; off; off >>= 1) s += __shfl_down(s, off, 64);
    __shared__ float red[4];
    if ((tid & 63) == 0) red[tid >> 6] = s;
    __syncthreads();
    if (tid == 0) sq[b] = red[0] + red[1] + red[2] + red[3];
}

// ---------------- kernel 2: GB = 0.5*Hi.Hi^T + Hi.Lo^T via MFMA ----------------
// XCD swizzle: ks = lin&7 pins each K-slice to one XCD's L2 (R5: FETCH 150->42MB).
__global__ __launch_bounds__(256) void k_gram_mfma(const ushort_t* __restrict__ xhi,
                                                   const ushort_t* __restrict__ xlo,
                                                   float* __restrict__ Gp) {
    int lin = blockIdx.x + 8 * blockIdx.y + 64 * blockIdx.z;
    int ks = lin & 7, bi = (lin >> 3) & 7, bj = lin >> 6;
    int i0 = bi * 128, j0 = bj * 128;
    int tid = threadIdx.x;
    int w = tid >> 6, lane = tid & 63;
    int wm = w & 1, wn = w >> 1;
    int quad = lane >> 4, m16 = lane & 15;
    int srow = lane >> 2, sseg = lane & 3;

    __shared__ __align__(16) ushort_t Ahi_s[128 * 32];
    __shared__ __align__(16) ushort_t Bhi_s[128 * 32];
    __shared__ __align__(16) ushort_t Blo_s[128 * 32];

    f32x4 acc[4][4];
    #pragma unroll
    for (int ii = 0; ii < 4; ++ii)
        #pragma unroll
        for (int jj = 0; jj < 4; ++jj)
            acc[ii][jj] = (f32x4){0.f, 0.f, 0.f, 0.f};

    const size_t Abase = (size_t)i0 * D;
    const size_t Bbase = (size_t)j0 * D;

    for (int kb = 0; kb < KSUB / 32; ++kb) {
        int k0 = ks * KSUB + kb * 32;
        #pragma unroll
        for (int c = 0; c < 2; ++c) {
            int r = w * 32 + c * 16 + srow;
            size_t go = (size_t)r * D + k0 + sseg * 8;
            int lo = (w * 32 + c * 16) * 32;
            gload_lds16(xhi + Abase + go, &Ahi_s[lo]);
            gload_lds16(xhi + Bbase + go, &Bhi_s[lo]);
            gload_lds16(xlo + Bbase + go, &Blo_s[lo]);
        }
        __syncthreads();

        bf16x8 ah[4], bh[4], bl[4];
        #pragma unroll
        for (int ii = 0; ii < 4; ++ii) {
            int ar = wm * 64 + ii * 16 + m16;
            ah[ii] = *(const bf16x8*)&Ahi_s[ar * 32 + quad * 8];
        }
        #pragma unroll
        for (int jj = 0; jj < 4; ++jj) {
            int br = wn * 64 + jj * 16 + m16;
            bh[jj] = *(const bf16x8*)&Bhi_s[br * 32 + quad * 8];
            bl[jj] = *(const bf16x8*)&Blo_s[br * 32 + quad * 8];
        }
        #pragma unroll
        for (int ii = 0; ii < 4; ++ii) {
            bf16x8 ahh = bf8_half(ah[ii]);
            #pragma unroll
            for (int jj = 0; jj < 4; ++jj) {
                acc[ii][jj] = __builtin_amdgcn_mfma_f32_16x16x32_bf16(ahh, bh[jj], acc[ii][jj], 0, 0, 0);
                acc[ii][jj] = __builtin_amdgcn_mfma_f32_16x16x32_bf16(ah[ii], bl[jj], acc[ii][jj], 0, 0, 0);
            }
        }
        __syncthreads();
    }

    float* Gb = Gp + (size_t)ks * NSAMP * NSAMP;
    #pragma unroll
    for (int ii = 0; ii < 4; ++ii)
        #pragma unroll
        for (int jj = 0; jj < 4; ++jj) {
            int rg = i0 + wm * 64 + ii * 16 + quad * 4;
            int cg = j0 + wn * 64 + jj * 16 + m16;
            #pragma unroll
            for (int r = 0; r < 4; ++r)
                Gb[(size_t)(rg + r) * NSAMP + cg] = acc[ii][jj][r];
        }
}

// ---------------- kernel 2b: fold partials + symmetrize: G = Sum_p + Sum_p^T ----
__global__ __launch_bounds__(256) void k_fold_sym(const float* __restrict__ Gp,
                                                  float* __restrict__ G) {
    int J = blockIdx.x, I = blockIdx.y;
    int t = threadIdx.x;
    int r = t >> 4, c4 = (t & 15) * 4;
    __shared__ float TJ[64][65];
    float4 sIJ[4];
    #pragma unroll
    for (int rr = 0; rr < 4; ++rr) {
        int row = rr * 16 + r;
        size_t oIJ = (size_t)(I * 64 + row) * NSAMP + J * 64 + c4;
        size_t oJI = (size_t)(J * 64 + row) * NSAMP + I * 64 + c4;
        float4 a = {0.f, 0.f, 0.f, 0.f}, bb = {0.f, 0.f, 0.f, 0.f};
        #pragma unroll
        for (int p = 0; p < KS; ++p) {
            float4 v = *(const float4*)(Gp + (size_t)p * NSAMP * NSAMP + oIJ);
            float4 w = *(const float4*)(Gp + (size_t)p * NSAMP * NSAMP + oJI);
            a.x += v.x; a.y += v.y; a.z += v.z; a.w += v.w;
            bb.x += w.x; bb.y += w.y; bb.z += w.z; bb.w += w.w;
        }
        sIJ[rr] = a;
        TJ[row][c4 + 0] = bb.x; TJ[row][c4 + 1] = bb.y;
        TJ[row][c4 + 2] = bb.z; TJ[row][c4 + 3] = bb.w;
    }
    __syncthreads();
    #pragma unroll
    for (int rr = 0; rr < 4; ++rr) {
        int row = rr * 16 + r;
        float4 v = sIJ[rr];
        v.x += TJ[c4 + 0][row]; v.y += TJ[c4 + 1][row];
        v.z += TJ[c4 + 2][row]; v.w += TJ[c4 + 3][row];
        *(float4*)(G + (size_t)(I * 64 + row) * NSAMP + J * 64 + c4) = v;
    }
}

// ---------------- kernel 3: hardest pos/neg + dsq init (row reads only) -----
__global__ void k_select(const float* __restrict__ G,
                         const float* __restrict__ sq, const int* __restrict__ tgt,
                         int* __restrict__ hp, int* __restrict__ hn,
                         float* __restrict__ dsq) {
    int i = blockIdx.x;
    int tid = threadIdx.x;
    float sqi = sq[i];
    int ti = tgt[i];
    float pv = -3.0e38f; int pj = 0x7FFFFFFF;
    float nv = 3.0e38f;  int nj = 0x7FFFFFFF;
    #pragma unroll
    for (int m = 0; m < 4; ++m) {
        int j = tid + 256 * m;
        float g = G[(size_t)i * NSAMP + j];
        float d2 = sqi + sq[j] - 2.f * g;
        float d = sqrtf(fmaxf(d2, 1e-12f));
        bool same = (tgt[j] == ti);
        float cp = same ? d : -1e30f;
        float cn = same ? 1e30f : d;
        if (cp > pv || (cp == pv && j < pj)) { pv = cp; pj = j; }
        if (cn < nv || (cn == nv && j < nj)) { nv = cn; nj = j; }
    }
    for (int off = 32; off; off >>= 1) {
        float opv = __shfl_down(pv, off, 64); int opj = __shfl_down(pj, off, 64);
        float onv = __shfl_down(nv, off, 64); int onj = __shfl_down(nj, off, 64);
        if (opv > pv || (opv == pv && opj < pj)) { pv = opv; pj = opj; }
        if (onv < nv || (onv == nv && onj < nj)) { nv = onv; nj = onj; }
    }
    __shared__ float spv[4], snv[4];
    __shared__ int spj[4], snj[4];
    if ((tid & 63) == 0) { int wv = tid >> 6; spv[wv] = pv; spj[wv] = pj; snv[wv] = nv; snj[wv] = nj; }
    __syncthreads();
    if (tid == 0) {
        for (int wv = 1; wv < 4; ++wv) {
            if (spv[wv] > pv || (spv[wv] == pv && spj[wv] < pj)) { pv = spv[wv]; pj = spj[wv]; }
            if (snv[wv] < nv || (snv[wv] == nv && snj[wv] < nj)) { nv = snv[wv]; nj = snj[wv]; }
        }
        hp[i] = pj; hn[i] = nj;
        // dsq = ||A||^2 init; k_dc adds (-2*Tr(A.M) + ||M||^2)
        dsq[i] = sqi; dsq[NSAMP + i] = sqi;
    }
}

// ---------------- kernel 4: DC align via MFMA, 32KB LDS, reg-pressure cut ----
// grid (b=1024, which=2), 4 waves. vs R6: (1) accM aliases accS (one acc[8][2]
// array serves both passes -> -64 VGPR peak); (2) transpose-read regs (trd)
// no longer span the softmax live-range (read moved after pf build; legal:
// softmax touches no LDS, O untouched between B1 and B2).
__global__ __launch_bounds__(256) void k_dc_mfma(const ushort_t* __restrict__ xhi,
                                                 const int* __restrict__ hp,
                                                 const int* __restrict__ hn,
                                                 float* __restrict__ dsq) {
    int b = blockIdx.x;
    int which = blockIdx.y;
    int oidx = (which == 0) ? hp[b] : hn[b];
    const ushort_t* Ag = xhi + (size_t)b * D;
    const ushort_t* Og = xhi + (size_t)oidx * D;

    __shared__ __align__(16) char smem[32768];   // O, then Ot in place

    int tid = threadIdx.x;
    int wv = tid >> 6, lane = tid & 63;
    int quad = lane >> 4, m16 = lane & 15;

    // A-frags from global (own rows per wave)
    bf16x8 af[2][4];
    #pragma unroll
    for (int tj2 = 0; tj2 < 2; ++tj2) {
        int r = (2 * wv + tj2) * 16 + m16;
        #pragma unroll
        for (int ks = 0; ks < 4; ++ks)
            af[tj2][ks] = *(const bf16x8*)(Ag + r * WH + ks * 32 + quad * 8);
    }

    // stage O into swizzled LDS
    {
        uint4 stg[8];
        #pragma unroll
        for (int k = 0; k < 8; ++k)
            stg[k] = *(const uint4*)((const char*)Og + (size_t)(tid + 256 * k) * 16);
        #pragma unroll
        for (int k = 0; k < 8; ++k) {
            int g = tid + 256 * k;
            *(uint4*)(smem + lds_off(g >> 4, (g & 15) * 8)) = stg[k];
        }
    }
    __syncthreads();   // B1: O staged

    // ---- S^T pass (acc serves as accS) ----
    f32x4 acc[8][2];
    #pragma unroll
    for (int ti = 0; ti < 8; ++ti)
        #pragma unroll
        for (int tj2 = 0; tj2 < 2; ++tj2)
            acc[ti][tj2] = (f32x4){0.f, 0.f, 0.f, 0.f};
    #pragma unroll
    for (int ks = 0; ks < 4; ++ks) {
        bf16x8 of[8];
        #pragma unroll
        for (int ti = 0; ti < 8; ++ti)
            of[ti] = *(const bf16x8*)(smem + lds_off(ti * 16 + m16, (ks * 4 + quad) * 8));
        #pragma unroll
        for (int ti = 0; ti < 8; ++ti)
            #pragma unroll
            for (int tj2 = 0; tj2 < 2; ++tj2)
                acc[ti][tj2] = __builtin_amdgcn_mfma_f32_16x16x32_bf16(of[ti], af[tj2][ks], acc[ti][tj2], 0, 0, 0);
    }

    // ---- softmax over c + in-register P-frag build (acc dies here) ----
    float tpart = 0.f;
    bf16x8 pf[2][4];
    #pragma unroll
    for (int tj2 = 0; tj2 < 2; ++tj2) {
        float mx = -3.0e38f;
        #pragma unroll
        for (int ti = 0; ti < 8; ++ti)
            #pragma unroll
            for (int r = 0; r < 4; ++r) {
                float s = acc[ti][tj2][r] * SCALE;
                acc[ti][tj2][r] = s;
                mx = fmaxf(mx, s);
            }
        mx = fmaxf(mx, __shfl_xor(mx, 16, 64));
        mx = fmaxf(mx, __shfl_xor(mx, 32, 64));
        float sum = 0.f, tnum = 0.f;
        #pragma unroll
        for (int ti = 0; ti < 8; ++ti)
            #pragma unroll
            for (int r = 0; r < 4; ++r) {
                float s = acc[ti][tj2][r];
                float e = __expf(s - mx);
                acc[ti][tj2][r] = e;
                sum += e;
                tnum += s * e;
            }
        sum += __shfl_xor(sum, 16, 64);
        sum += __shfl_xor(sum, 32, 64);
        tnum += __shfl_xor(tnum, 16, 64);
        tnum += __shfl_xor(tnum, 32, 64);
        float inv = 1.f / sum;
        tpart += 0.25f * tnum * inv;       // all 4 quads add the full row sum

        uint Ep[8][2];
        #pragma unroll
        for (int ti = 0; ti < 8; ++ti) {
            Ep[ti][0] = (uint)f2bf(acc[ti][tj2][0] * inv) |
                        ((uint)f2bf(acc[ti][tj2][1] * inv) << 16);
            Ep[ti][1] = (uint)f2bf(acc[ti][tj2][2] * inv) |
                        ((uint)f2bf(acc[ti][tj2][3] * inv) << 16);
        }
        int tih = quad >> 1;
        #pragma unroll
        for (int ks = 0; ks < 4; ++ks) {
            union { uint u[4]; bf16x8 v; } fr;
            #pragma unroll
            for (int k = 0; k < 4; ++k) {
                int src = (((quad << 1) + (k >> 1)) & 3) * 16 + m16;
                int a = __shfl((int)Ep[2 * ks + 0][k & 1], src, 64);
                int bsh = __shfl((int)Ep[2 * ks + 1][k & 1], src, 64);
                fr.u[k] = (uint)((tih == 0) ? a : bsh);
            }
            pf[tj2][ks] = fr.v;
        }
    }

    // ---- transpose read (O still valid; trd live-range starts here) ----
    int c0 = (tid & 31) * 4, h0 = (tid >> 5) * 16;
    uint4 trd[4][2];
    #pragma unroll
    for (int j = 0; j < 4; ++j)
        #pragma unroll
        for (int k = 0; k < 2; ++k)
            trd[j][k] = *(const uint4*)(smem + lds_off(c0 + j, h0 + 8 * k));
    __syncthreads();   // B2: all O reads done

    // transpose write: (c,h) -> (h,c) in place
    #pragma unroll
    for (int i = 0; i < 16; ++i) {
        uint v[4];
        #pragma unroll
        for (int j = 0; j < 4; ++j) {
            uint wo = ((const uint*)&trd[j][i >> 3])[(i >> 1) & 3];
            v[j] = (i & 1) ? (wo >> 16) : (wo & 0xffffu);
        }
        uint2 pk;
        pk.x = v[0] | (v[1] << 16);
        pk.y = v[2] | (v[3] << 16);
        *(uint2*)(smem + lds_off(h0 + i, c0)) = pk;
    }
    __syncthreads();   // B3: Ot complete

    // ---- M pass: reuse acc as accM (acc[tj][tj2] == accM[tj2][tj]) ----
    #pragma unroll
    for (int tj = 0; tj < 8; ++tj)
        #pragma unroll
        for (int tj2 = 0; tj2 < 2; ++tj2)
            acc[tj][tj2] = (f32x4){0.f, 0.f, 0.f, 0.f};
    #pragma unroll
    for (int ks = 0; ks < 4; ++ks) {
        bf16x8 otf[8];
        #pragma unroll
        for (int tj = 0; tj < 8; ++tj)
            otf[tj] = *(const bf16x8*)(smem + lds_off(tj * 16 + m16, (ks * 4 + quad) * 8));
        #pragma unroll
        for (int tj2 = 0; tj2 < 2; ++tj2)
            #pragma unroll
            for (int tj = 0; tj < 8; ++tj)
                acc[tj][tj2] = __builtin_amdgcn_mfma_f32_16x16x32_bf16(pf[tj2][ks], otf[tj], acc[tj][tj2], 0, 0, 0);
    }

    float m2 = 0.f;
    #pragma unroll
    for (int tj = 0; tj < 8; ++tj)
        #pragma unroll
        for (int tj2 = 0; tj2 < 2; ++tj2)
            #pragma unroll
            for (int r = 0; r < 4; ++r) {
                float mvv = acc[tj][tj2][r];
                m2 += mvv * mvv;
            }
    float part = m2 - 2.f * RSCALE * tpart;
    for (int off = 32; off; off >>= 1) part += __shfl_down(part, off, 64);
    if (lane == 0) atomicAdd(&dsq[which * NSAMP + b], part);
}

// ---------------- kernel 5: final loss ----------------
__global__ void k_loss(const float* __restrict__ dsq, float* __restrict__ out) {
    int tid = threadIdx.x;
    float s = 0.f;
    #pragma unroll
    for (int m = 0; m < 4; ++m) {
        int b = tid + 256 * m;
        float ap = sqrtf(fmaxf(dsq[b], 0.f));
        float an = sqrtf(fmaxf(dsq[NSAMP + b], 0.f));
        s += fmaxf(ap - an + MARGIN, 0.f);
    }
    for (int off = 32; off; off >>= 1) s += __shfl_down(s, off, 64);
    __shared__ float red[4];
    if ((tid & 63) == 0) red[tid >> 6] = s;
    __syncthreads();
    if (tid == 0) out[0] = (red[0] + red[1] + red[2] + red[3]) * (1.f / NSAMP);
}

extern "C" void kernel_launch(void* const* d_in, const int* in_sizes, int n_in,
                              void* d_out, int out_size, void* d_ws, size_t ws_size,
                              hipStream_t stream) {
    const float* x = (const float*)d_in[0];
    const int* tgt = (const int*)d_in[1];
    float* out = (float*)d_out;
    char* ws = (char*)d_ws;

    float* Gp = (float*)ws;                                       // KS * 4 MB = 32 MB
    ushort_t* xhi = (ushort_t*)(ws + (size_t)32 * 1024 * 1024);   // 32 MB
    ushort_t* xlo = xhi + (size_t)NSAMP * D;                      // 32 MB (dead after gram)
    float* G = (float*)xlo;                                       // 4 MB, overlays xlo
    float* sq = (float*)(ws + (size_t)96 * 1024 * 1024);          // 4 KB
    float* dsq = sq + NSAMP;                                      // 8 KB
    int* hp = (int*)(dsq + 2 * NSAMP);                            // 4 KB
    int* hn = hp + NSAMP;                                         // 4 KB

    k_norms_split<<<NSAMP, 256, 0, stream>>>(x, sq, xhi, xlo);
    k_gram_mfma<<<dim3(8, 8, 8), 256, 0, stream>>>(xhi, xlo, Gp);
    k_fold_sym<<<dim3(16, 16), 256, 0, stream>>>(Gp, G);
    k_select<<<NSAMP, 256, 0, stream>>>(G, sq, tgt, hp, hn, dsq);
    k_dc_mfma<<<dim3(NSAMP, 2), 256, 0, stream>>>(xhi, hp, hn, dsq);
    k_loss<<<1, 256, 0, stream>>>(dsq, out);
}

// Round 9
// 231.110 us; speedup vs baseline: 1.2484x; 1.0864x over previous
//
#include <hip/hip_runtime.h>
#include <stdint.h>

#define NSAMP 1024
#define D 16384
#define WH 128
#define MARGIN 0.3f
#define KS 8
#define KSUB (D / KS)
#define SCALE 0.08838834764831845f    // 1/sqrt(128)
#define RSCALE 11.313708498984761f    // sqrt(128)

typedef unsigned int uint;
typedef unsigned short ushort_t;

typedef __attribute__((ext_vector_type(8))) short bf16x8;   // 8 bf16 = 4 VGPRs
typedef __attribute__((ext_vector_type(4))) float f32x4;

__device__ __forceinline__ float bf2f(unsigned short b) {
    return __uint_as_float(((uint)b) << 16);
}
__device__ __forceinline__ unsigned short f2bf(float f) {
    uint u = __float_as_uint(f);
    u += 0x7fffu + ((u >> 16) & 1u);   // RNE (data has no NaN)
    return (unsigned short)(u >> 16);
}
__device__ __forceinline__ void gload_lds16(const void* g, void* l) {
    __builtin_amdgcn_global_load_lds(
        (const __attribute__((address_space(1))) uint32_t*)g,
        (__attribute__((address_space(3))) uint32_t*)l, 16, 0, 0);
}
// Halve all 8 bf16 lanes: exponent-field decrement (exact; hi-split of N(0,1)
// data is never subnormal/zero, so no borrow).
__device__ __forceinline__ bf16x8 bf8_half(bf16x8 v) {
    union { bf16x8 b; uint u[4]; } c;
    c.b = v;
    c.u[0] -= 0x00800080u; c.u[1] -= 0x00800080u;
    c.u[2] -= 0x00800080u; c.u[3] -= 0x00800080u;
    return c.b;
}
// Swizzled LDS byte offset for a 128-col bf16 row-major tile.
__device__ __forceinline__ int lds_off(int row, int col) {
    return row * 256 + ((((col >> 3) ^ (row & 15)) << 4) | ((col & 7) << 1));
}

// ---------------- kernel 1: row norms + hi/lo bf16 split ----------------
__global__ __launch_bounds__(256) void k_norms_split(const float* __restrict__ x,
                                                     float* __restrict__ sq,
                                                     ushort_t* __restrict__ xhi,
                                                     ushort_t* __restrict__ xlo) {
    int b = blockIdx.x;
    int tid = threadIdx.x;
    const float* xr = x + (size_t)b * D;
    ushort_t* hr = xhi + (size_t)b * D;
    ushort_t* lr = xlo + (size_t)b * D;
    float s = 0.f;
    #pragma unroll
    for (int m = 0; m < 16; ++m) {
        int e = m * 1024 + tid * 4;
        float4 v = *(const float4*)(xr + e);
        s += v.x * v.x + v.y * v.y + v.z * v.z + v.w * v.w;
        ushort4 h, l;
        h.x = f2bf(v.x); l.x = f2bf(v.x - bf2f(h.x));
        h.y = f2bf(v.y); l.y = f2bf(v.y - bf2f(h.y));
        h.z = f2bf(v.z); l.z = f2bf(v.z - bf2f(h.z));
        h.w = f2bf(v.w); l.w = f2bf(v.w - bf2f(h.w));
        *(ushort4*)(hr + e) = h;
        *(ushort4*)(lr + e) = l;
    }
    for (int off = 32; off; off >>= 1) s += __shfl_down(s, off, 64);
    __shared__ float red[4];
    if ((tid & 63) == 0) red[tid >> 6] = s;
    __syncthreads();
    if (tid == 0) sq[b] = red[0] + red[1] + red[2] + red[3];
}

// ---------------- kernel 2: GB = 0.5*Hi.Hi^T + Hi.Lo^T via MFMA ----------------
// XCD swizzle: ks = lin&7 pins each K-slice to one XCD's L2 (R5: FETCH 150->42MB).
__global__ __launch_bounds__(256) void k_gram_mfma(const ushort_t* __restrict__ xhi,
                                                   const ushort_t* __restrict__ xlo,
                                                   float* __restrict__ Gp) {
    int lin = blockIdx.x + 8 * blockIdx.y + 64 * blockIdx.z;
    int ks = lin & 7, bi = (lin >> 3) & 7, bj = lin >> 6;
    int i0 = bi * 128, j0 = bj * 128;
    int tid = threadIdx.x;
    int w = tid >> 6, lane = tid & 63;
    int wm = w & 1, wn = w >> 1;
    int quad = lane >> 4, m16 = lane & 15;
    int srow = lane >> 2, sseg = lane & 3;

    __shared__ __align__(16) ushort_t Ahi_s[128 * 32];
    __shared__ __align__(16) ushort_t Bhi_s[128 * 32];
    __shared__ __align__(16) ushort_t Blo_s[128 * 32];

    f32x4 acc[4][4];
    #pragma unroll
    for (int ii = 0; ii < 4; ++ii)
        #pragma unroll
        for (int jj = 0; jj < 4; ++jj)
            acc[ii][jj] = (f32x4){0.f, 0.f, 0.f, 0.f};

    const size_t Abase = (size_t)i0 * D;
    const size_t Bbase = (size_t)j0 * D;

    for (int kb = 0; kb < KSUB / 32; ++kb) {
        int k0 = ks * KSUB + kb * 32;
        #pragma unroll
        for (int c = 0; c < 2; ++c) {
            int r = w * 32 + c * 16 + srow;
            size_t go = (size_t)r * D + k0 + sseg * 8;
            int lo = (w * 32 + c * 16) * 32;
            gload_lds16(xhi + Abase + go, &Ahi_s[lo]);
            gload_lds16(xhi + Bbase + go, &Bhi_s[lo]);
            gload_lds16(xlo + Bbase + go, &Blo_s[lo]);
        }
        __syncthreads();

        bf16x8 ah[4], bh[4], bl[4];
        #pragma unroll
        for (int ii = 0; ii < 4; ++ii) {
            int ar = wm * 64 + ii * 16 + m16;
            ah[ii] = *(const bf16x8*)&Ahi_s[ar * 32 + quad * 8];
        }
        #pragma unroll
        for (int jj = 0; jj < 4; ++jj) {
            int br = wn * 64 + jj * 16 + m16;
            bh[jj] = *(const bf16x8*)&Bhi_s[br * 32 + quad * 8];
            bl[jj] = *(const bf16x8*)&Blo_s[br * 32 + quad * 8];
        }
        #pragma unroll
        for (int ii = 0; ii < 4; ++ii) {
            bf16x8 ahh = bf8_half(ah[ii]);
            #pragma unroll
            for (int jj = 0; jj < 4; ++jj) {
                acc[ii][jj] = __builtin_amdgcn_mfma_f32_16x16x32_bf16(ahh, bh[jj], acc[ii][jj], 0, 0, 0);
                acc[ii][jj] = __builtin_amdgcn_mfma_f32_16x16x32_bf16(ah[ii], bl[jj], acc[ii][jj], 0, 0, 0);
            }
        }
        __syncthreads();
    }

    float* Gb = Gp + (size_t)ks * NSAMP * NSAMP;
    #pragma unroll
    for (int ii = 0; ii < 4; ++ii)
        #pragma unroll
        for (int jj = 0; jj < 4; ++jj) {
            int rg = i0 + wm * 64 + ii * 16 + quad * 4;
            int cg = j0 + wn * 64 + jj * 16 + m16;
            #pragma unroll
            for (int r = 0; r < 4; ++r)
                Gb[(size_t)(rg + r) * NSAMP + cg] = acc[ii][jj][r];
        }
}

// ---------------- kernel 2b: fold partials + symmetrize: G = Sum_p + Sum_p^T ----
__global__ __launch_bounds__(256) void k_fold_sym(const float* __restrict__ Gp,
                                                  float* __restrict__ G) {
    int J = blockIdx.x, I = blockIdx.y;
    int t = threadIdx.x;
    int r = t >> 4, c4 = (t & 15) * 4;
    __shared__ float TJ[64][65];
    float4 sIJ[4];
    #pragma unroll
    for (int rr = 0; rr < 4; ++rr) {
        int row = rr * 16 + r;
        size_t oIJ = (size_t)(I * 64 + row) * NSAMP + J * 64 + c4;
        size_t oJI = (size_t)(J * 64 + row) * NSAMP + I * 64 + c4;
        float4 a = {0.f, 0.f, 0.f, 0.f}, bb = {0.f, 0.f, 0.f, 0.f};
        #pragma unroll
        for (int p = 0; p < KS; ++p) {
            float4 v = *(const float4*)(Gp + (size_t)p * NSAMP * NSAMP + oIJ);
            float4 w = *(const float4*)(Gp + (size_t)p * NSAMP * NSAMP + oJI);
            a.x += v.x; a.y += v.y; a.z += v.z; a.w += v.w;
            bb.x += w.x; bb.y += w.y; bb.z += w.z; bb.w += w.w;
        }
        sIJ[rr] = a;
        TJ[row][c4 + 0] = bb.x; TJ[row][c4 + 1] = bb.y;
        TJ[row][c4 + 2] = bb.z; TJ[row][c4 + 3] = bb.w;
    }
    __syncthreads();
    #pragma unroll
    for (int rr = 0; rr < 4; ++rr) {
        int row = rr * 16 + r;
        float4 v = sIJ[rr];
        v.x += TJ[c4 + 0][row]; v.y += TJ[c4 + 1][row];
        v.z += TJ[c4 + 2][row]; v.w += TJ[c4 + 3][row];
        *(float4*)(G + (size_t)(I * 64 + row) * NSAMP + J * 64 + c4) = v;
    }
}

// ---------------- kernel 3: hardest pos/neg + dsq init (row reads only) -----
__global__ void k_select(const float* __restrict__ G,
                         const float* __restrict__ sq, const int* __restrict__ tgt,
                         int* __restrict__ hp, int* __restrict__ hn,
                         float* __restrict__ dsq) {
    int i = blockIdx.x;
    int tid = threadIdx.x;
    float sqi = sq[i];
    int ti = tgt[i];
    float pv = -3.0e38f; int pj = 0x7FFFFFFF;
    float nv = 3.0e38f;  int nj = 0x7FFFFFFF;
    #pragma unroll
    for (int m = 0; m < 4; ++m) {
        int j = tid + 256 * m;
        float g = G[(size_t)i * NSAMP + j];
        float d2 = sqi + sq[j] - 2.f * g;
        float d = sqrtf(fmaxf(d2, 1e-12f));
        bool same = (tgt[j] == ti);
        float cp = same ? d : -1e30f;
        float cn = same ? 1e30f : d;
        if (cp > pv || (cp == pv && j < pj)) { pv = cp; pj = j; }
        if (cn < nv || (cn == nv && j < nj)) { nv = cn; nj = j; }
    }
    for (int off = 32; off; off >>= 1) {
        float opv = __shfl_down(pv, off, 64); int opj = __shfl_down(pj, off, 64);
        float onv = __shfl_down(nv, off, 64); int onj = __shfl_down(nj, off, 64);
        if (opv > pv || (opv == pv && opj < pj)) { pv = opv; pj = opj; }
        if (onv < nv || (onv == nv && onj < nj)) { nv = onv; nj = onj; }
    }
    __shared__ float spv[4], snv[4];
    __shared__ int spj[4], snj[4];
    if ((tid & 63) == 0) { int wv = tid >> 6; spv[wv] = pv; spj[wv] = pj; snv[wv] = nv; snj[wv] = nj; }
    __syncthreads();
    if (tid == 0) {
        for (int wv = 1; wv < 4; ++wv) {
            if (spv[wv] > pv || (spv[wv] == pv && spj[wv] < pj)) { pv = spv[wv]; pj = spj[wv]; }
            if (snv[wv] < nv || (snv[wv] == nv && snj[wv] < nj)) { nv = snv[wv]; nj = snj[wv]; }
        }
        hp[i] = pj; hn[i] = nj;
        // dsq = ||A||^2 init; k_dc adds (-2*Tr(A.M) + ||M||^2)
        dsq[i] = sqi; dsq[NSAMP + i] = sqi;
    }
}

// ---------------- kernel 4: DC align via MFMA, 64-row blocks ----------------
// grid (b=1024, which=2, q=2), 4 waves; wave wv owns rows rt*16.. (rt=q*4+wv).
// R6 phase order preserved exactly (S -> trd-read -> B2 -> transpose-write ->
// softmax+pf -> B3 -> M); per-wave state halved, 2x blocks for latency hiding.
__global__ __launch_bounds__(256) void k_dc_mfma(const ushort_t* __restrict__ xhi,
                                                 const int* __restrict__ hp,
                                                 const int* __restrict__ hn,
                                                 float* __restrict__ dsq) {
    int b = blockIdx.x;
    int which = blockIdx.y;
    int q = blockIdx.z;
    int oidx = (which == 0) ? hp[b] : hn[b];
    const ushort_t* Ag = xhi + (size_t)b * D;
    const ushort_t* Og = xhi + (size_t)oidx * D;

    __shared__ __align__(16) char smem[32768];   // O, then Ot in place

    int tid = threadIdx.x;
    int wv = tid >> 6, lane = tid & 63;
    int quad = lane >> 4, m16 = lane & 15;
    int rt = q * 4 + wv;                 // this wave's 16-row tile

    // A-frags from global (own rows)
    bf16x8 af[4];
    #pragma unroll
    for (int ks = 0; ks < 4; ++ks)
        af[ks] = *(const bf16x8*)(Ag + (rt * 16 + m16) * WH + ks * 32 + quad * 8);

    // stage O into swizzled LDS
    {
        uint4 stg[8];
        #pragma unroll
        for (int k = 0; k < 8; ++k)
            stg[k] = *(const uint4*)((const char*)Og + (size_t)(tid + 256 * k) * 16);
        #pragma unroll
        for (int k = 0; k < 8; ++k) {
            int g = tid + 256 * k;
            *(uint4*)(smem + lds_off(g >> 4, (g & 15) * 8)) = stg[k];
        }
    }
    __syncthreads();   // B1: O staged

    // ---- S^T pass: acc[ti] covers S[c=ti*16+quad*4+reg][r=rt*16+m16] ----
    f32x4 acc[8];
    #pragma unroll
    for (int ti = 0; ti < 8; ++ti)
        acc[ti] = (f32x4){0.f, 0.f, 0.f, 0.f};
    #pragma unroll
    for (int ks = 0; ks < 4; ++ks) {
        bf16x8 of[8];
        #pragma unroll
        for (int ti = 0; ti < 8; ++ti)
            of[ti] = *(const bf16x8*)(smem + lds_off(ti * 16 + m16, (ks * 4 + quad) * 8));
        #pragma unroll
        for (int ti = 0; ti < 8; ++ti)
            acc[ti] = __builtin_amdgcn_mfma_f32_16x16x32_bf16(of[ti], af[ks], acc[ti], 0, 0, 0);
    }

    // ---- transpose read (O still valid) ----
    int c0 = (tid & 31) * 4, h0 = (tid >> 5) * 16;
    uint4 trd[4][2];
    #pragma unroll
    for (int j = 0; j < 4; ++j)
        #pragma unroll
        for (int k = 0; k < 2; ++k)
            trd[j][k] = *(const uint4*)(smem + lds_off(c0 + j, h0 + 8 * k));
    __syncthreads();   // B2: all O reads done

    // transpose write: (c,h) -> (h,c) in place
    #pragma unroll
    for (int i = 0; i < 16; ++i) {
        uint v[4];
        #pragma unroll
        for (int j = 0; j < 4; ++j) {
            uint wo = ((const uint*)&trd[j][i >> 3])[(i >> 1) & 3];
            v[j] = (i & 1) ? (wo >> 16) : (wo & 0xffffu);
        }
        uint2 pk;
        pk.x = v[0] | (v[1] << 16);
        pk.y = v[2] | (v[3] << 16);
        *(uint2*)(smem + lds_off(h0 + i, c0)) = pk;
    }

    // ---- softmax over c + in-register P-frag build (fills B2->B3 gap) ----
    float tpart = 0.f;
    bf16x8 pf[4];
    {
        float mx = -3.0e38f;
        #pragma unroll
        for (int ti = 0; ti < 8; ++ti)
            #pragma unroll
            for (int r = 0; r < 4; ++r) {
                float s = acc[ti][r] * SCALE;
                acc[ti][r] = s;
                mx = fmaxf(mx, s);
            }
        mx = fmaxf(mx, __shfl_xor(mx, 16, 64));
        mx = fmaxf(mx, __shfl_xor(mx, 32, 64));
        float sum = 0.f, tnum = 0.f;
        #pragma unroll
        for (int ti = 0; ti < 8; ++ti)
            #pragma unroll
            for (int r = 0; r < 4; ++r) {
                float s = acc[ti][r];
                float e = __expf(s - mx);
                acc[ti][r] = e;
                sum += e;
                tnum += s * e;
            }
        sum += __shfl_xor(sum, 16, 64);
        sum += __shfl_xor(sum, 32, 64);
        tnum += __shfl_xor(tnum, 16, 64);
        tnum += __shfl_xor(tnum, 32, 64);
        float inv = 1.f / sum;
        tpart = 0.25f * tnum * inv;        // all 4 quads add the full row sum

        uint Ep[8][2];
        #pragma unroll
        for (int ti = 0; ti < 8; ++ti) {
            Ep[ti][0] = (uint)f2bf(acc[ti][0] * inv) |
                        ((uint)f2bf(acc[ti][1] * inv) << 16);
            Ep[ti][1] = (uint)f2bf(acc[ti][2] * inv) |
                        ((uint)f2bf(acc[ti][3] * inv) << 16);
        }
        int tih = quad >> 1;
        #pragma unroll
        for (int ks = 0; ks < 4; ++ks) {
            union { uint u[4]; bf16x8 v; } fr;
            #pragma unroll
            for (int k = 0; k < 4; ++k) {
                int src = (((quad << 1) + (k >> 1)) & 3) * 16 + m16;
                int a = __shfl((int)Ep[2 * ks + 0][k & 1], src, 64);
                int bsh = __shfl((int)Ep[2 * ks + 1][k & 1], src, 64);
                fr.u[k] = (uint)((tih == 0) ? a : bsh);
            }
            pf[ks] = fr.v;
        }
    }
    __syncthreads();   // B3: Ot complete

    // ---- M pass: M = P . O via MFMA(pf, Ot rows); reuse acc ----
    #pragma unroll
    for (int tj = 0; tj < 8; ++tj)
        acc[tj] = (f32x4){0.f, 0.f, 0.f, 0.f};
    #pragma unroll
    for (int ks = 0; ks < 4; ++ks) {
        bf16x8 otf[8];
        #pragma unroll
        for (int tj = 0; tj < 8; ++tj)
            otf[tj] = *(const bf16x8*)(smem + lds_off(tj * 16 + m16, (ks * 4 + quad) * 8));
        #pragma unroll
        for (int tj = 0; tj < 8; ++tj)
            acc[tj] = __builtin_amdgcn_mfma_f32_16x16x32_bf16(pf[ks], otf[tj], acc[tj], 0, 0, 0);
    }

    float m2 = 0.f;
    #pragma unroll
    for (int tj = 0; tj < 8; ++tj)
        #pragma unroll
        for (int r = 0; r < 4; ++r) {
            float mvv = acc[tj][r];
            m2 += mvv * mvv;
        }
    float part = m2 - 2.f * RSCALE * tpart;
    for (int off = 32; off; off >>= 1) part += __shfl_down(part, off, 64);
    if (lane == 0) atomicAdd(&dsq[which * NSAMP + b], part);
}

// ---------------- kernel 5: final loss ----------------
__global__ void k_loss(const float* __restrict__ dsq, float* __restrict__ out) {
    int tid = threadIdx.x;
    float s = 0.f;
    #pragma unroll
    for (int m = 0; m < 4; ++m) {
        int b = tid + 256 * m;
        float ap = sqrtf(fmaxf(dsq[b], 0.f));
        float an = sqrtf(fmaxf(dsq[NSAMP + b], 0.f));
        s += fmaxf(ap - an + MARGIN, 0.f);
    }
    for (int off = 32; off; off >>= 1) s += __shfl_down(s, off, 64);
    __shared__ float red[4];
    if ((tid & 63) == 0) red[tid >> 6] = s;
    __syncthreads();
    if (tid == 0) out[0] = (red[0] + red[1] + red[2] + red[3]) * (1.f / NSAMP);
}

extern "C" void kernel_launch(void* const* d_in, const int* in_sizes, int n_in,
                              void* d_out, int out_size, void* d_ws, size_t ws_size,
                              hipStream_t stream) {
    const float* x = (const float*)d_in[0];
    const int* tgt = (const int*)d_in[1];
    float* out = (float*)d_out;
    char* ws = (char*)d_ws;

    float* Gp = (float*)ws;                                       // KS * 4 MB = 32 MB
    ushort_t* xhi = (ushort_t*)(ws + (size_t)32 * 1024 * 1024);   // 32 MB
    ushort_t* xlo = xhi + (size_t)NSAMP * D;                      // 32 MB (dead after gram)
    float* G = (float*)xlo;                                       // 4 MB, overlays xlo
    float* sq = (float*)(ws + (size_t)96 * 1024 * 1024);          // 4 KB
    float* dsq = sq + NSAMP;                                      // 8 KB
    int* hp = (int*)(dsq + 2 * NSAMP);                            // 4 KB
    int* hn = hp + NSAMP;                                         // 4 KB

    k_norms_split<<<NSAMP, 256, 0, stream>>>(x, sq, xhi, xlo);
    k_gram_mfma<<<dim3(8, 8, 8), 256, 0, stream>>>(xhi, xlo, Gp);
    k_fold_sym<<<dim3(16, 16), 256, 0, stream>>>(Gp, G);
    k_select<<<NSAMP, 256, 0, stream>>>(G, sq, tgt, hp, hn, dsq);
    k_dc_mfma<<<dim3(NSAMP, 2, 2), 256, 0, stream>>>(xhi, hp, hn, dsq);
    k_loss<<<1, 256, 0, stream>>>(dsq, out);
}

// Round 10
// 228.930 us; speedup vs baseline: 1.2602x; 1.0095x over previous
//
#include <hip/hip_runtime.h>
#include <stdint.h>

#define NSAMP 1024
#define D 16384
#define WH 128
#define MARGIN 0.3f
#define SCALE 0.08838834764831845f    // 1/sqrt(128)
#define RSCALE 11.313708498984761f    // sqrt(128)
#define MARG 0.03f                    // selection ambiguity margin (d units)
#define LISTCAP 2048

typedef unsigned int uint;
typedef unsigned short ushort_t;

typedef __attribute__((ext_vector_type(8))) short bf16x8;   // 8 bf16 = 4 VGPRs
typedef __attribute__((ext_vector_type(4))) float f32x4;

__device__ __forceinline__ float bf2f(unsigned short b) {
    return __uint_as_float(((uint)b) << 16);
}
__device__ __forceinline__ unsigned short f2bf(float f) {
    uint u = __float_as_uint(f);
    u += 0x7fffu + ((u >> 16) & 1u);   // RNE (data has no NaN)
    return (unsigned short)(u >> 16);
}
__device__ __forceinline__ void gload_lds16(const void* g, void* l) {
    __builtin_amdgcn_global_load_lds(
        (const __attribute__((address_space(1))) uint32_t*)g,
        (__attribute__((address_space(3))) uint32_t*)l, 16, 0, 0);
}
// Swizzled LDS byte offset for a 128-col bf16 row-major tile.
__device__ __forceinline__ int lds_off(int row, int col) {
    return row * 256 + ((((col >> 3) ^ (row & 15)) << 4) | ((col & 7) << 1));
}

// ---------------- kernel 1: row norms (fp32) + hi bf16 cast ----------------
__global__ __launch_bounds__(256) void k_norms_hi(const float* __restrict__ x,
                                                  float* __restrict__ sq,
                                                  ushort_t* __restrict__ xhi) {
    int b = blockIdx.x;
    int tid = threadIdx.x;
    const float* xr = x + (size_t)b * D;
    ushort_t* hr = xhi + (size_t)b * D;
    float s = 0.f;
    #pragma unroll
    for (int m = 0; m < 16; ++m) {
        int e = m * 1024 + tid * 4;
        float4 v = *(const float4*)(xr + e);
        s += v.x * v.x + v.y * v.y + v.z * v.z + v.w * v.w;
        ushort4 h;
        h.x = f2bf(v.x); h.y = f2bf(v.y); h.z = f2bf(v.z); h.w = f2bf(v.w);
        *(ushort4*)(hr + e) = h;
    }
    for (int off = 32; off; off >>= 1) s += __shfl_down(s, off, 64);
    __shared__ float red[4];
    if ((tid & 63) == 0) red[tid >> 6] = s;
    __syncthreads();
    if (tid == 0) sq[b] = red[0] + red[1] + red[2] + red[3];
}

// ---------------- kernel 2: G~ = Hi.Hi^T partials via MFMA ----------------
// grid (ks=nks, bi=8, bj=8): ks fastest -> XCD-pinned K-slices.
// K=64 per barrier pair (two 32-chunks), 32 MFMA/barrier/wave.
__global__ __launch_bounds__(256) void k_gram_hi(const ushort_t* __restrict__ xhi,
                                                 float* __restrict__ Gp, int ksub) {
    int ks = blockIdx.x, bi = blockIdx.y, bj = blockIdx.z;
    int i0 = bi * 128, j0 = bj * 128;
    int tid = threadIdx.x;
    int w = tid >> 6, lane = tid & 63;
    int wm = w & 1, wn = w >> 1;
    int quad = lane >> 4, m16 = lane & 15;
    int srow = lane >> 2, sseg = lane & 3;

    __shared__ __align__(16) ushort_t A_s[2][128 * 32];
    __shared__ __align__(16) ushort_t B_s[2][128 * 32];

    f32x4 acc[4][4];
    #pragma unroll
    for (int ii = 0; ii < 4; ++ii)
        #pragma unroll
        for (int jj = 0; jj < 4; ++jj)
            acc[ii][jj] = (f32x4){0.f, 0.f, 0.f, 0.f};

    const size_t Abase = (size_t)i0 * D;
    const size_t Bbase = (size_t)j0 * D;

    for (int kb = 0; kb < ksub / 64; ++kb) {
        int k0 = ks * ksub + kb * 64;
        #pragma unroll
        for (int kk = 0; kk < 2; ++kk) {
            #pragma unroll
            for (int c = 0; c < 2; ++c) {
                int r = w * 32 + c * 16 + srow;
                size_t go = (size_t)r * D + k0 + kk * 32 + sseg * 8;
                int lo = (w * 32 + c * 16) * 32;
                gload_lds16(xhi + Abase + go, &A_s[kk][lo]);
                gload_lds16(xhi + Bbase + go, &B_s[kk][lo]);
            }
        }
        __syncthreads();

        #pragma unroll
        for (int kk = 0; kk < 2; ++kk) {
            bf16x8 ah[4], bh[4];
            #pragma unroll
            for (int ii = 0; ii < 4; ++ii) {
                int ar = wm * 64 + ii * 16 + m16;
                ah[ii] = *(const bf16x8*)&A_s[kk][ar * 32 + quad * 8];
            }
            #pragma unroll
            for (int jj = 0; jj < 4; ++jj) {
                int br = wn * 64 + jj * 16 + m16;
                bh[jj] = *(const bf16x8*)&B_s[kk][br * 32 + quad * 8];
            }
            #pragma unroll
            for (int ii = 0; ii < 4; ++ii)
                #pragma unroll
                for (int jj = 0; jj < 4; ++jj)
                    acc[ii][jj] = __builtin_amdgcn_mfma_f32_16x16x32_bf16(ah[ii], bh[jj], acc[ii][jj], 0, 0, 0);
        }
        __syncthreads();
    }

    float* Gb = Gp + (size_t)ks * NSAMP * NSAMP;
    #pragma unroll
    for (int ii = 0; ii < 4; ++ii)
        #pragma unroll
        for (int jj = 0; jj < 4; ++jj) {
            int rg = i0 + wm * 64 + ii * 16 + quad * 4;
            int cg = j0 + wn * 64 + jj * 16 + m16;
            #pragma unroll
            for (int r = 0; r < 4; ++r)
                Gb[(size_t)(rg + r) * NSAMP + cg] = acc[ii][jj][r];
        }
}

// ---------------- kernel 2b: fold partials (no transpose; G~ symmetric) ----
__global__ __launch_bounds__(256) void k_fold(const float* __restrict__ Gp,
                                              float* __restrict__ G, int nks,
                                              int* __restrict__ cnt) {
    if (blockIdx.x == 0 && threadIdx.x == 0) cnt[0] = 0;
    size_t idx = ((size_t)blockIdx.x * 256 + threadIdx.x) * 4;
    float4 s = *(const float4*)(Gp + idx);
    for (int p = 1; p < nks; ++p) {
        float4 v = *(const float4*)(Gp + (size_t)p * NSAMP * NSAMP + idx);
        s.x += v.x; s.y += v.y; s.z += v.z; s.w += v.w;
    }
    *(float4*)(G + idx) = s;
}

// ---------------- kernel 3: select + ambiguity flagging ----------------
__global__ void k_select_flag(const float* __restrict__ G,
                              const float* __restrict__ sq, const int* __restrict__ tgt,
                              int* __restrict__ hp, int* __restrict__ hn,
                              float* __restrict__ dsq, float* __restrict__ bestd,
                              int* __restrict__ list, int* __restrict__ cnt) {
    int i = blockIdx.x;
    int tid = threadIdx.x;
    float sqi = sq[i];
    int ti = tgt[i];
    float dloc[4]; bool sloc[4];
    float pv = -3.0e38f; int pj = 0x7FFFFFFF;
    float nv = 3.0e38f;  int nj = 0x7FFFFFFF;
    #pragma unroll
    for (int m = 0; m < 4; ++m) {
        int j = tid + 256 * m;
        float g = G[(size_t)i * NSAMP + j];
        float d = sqrtf(fmaxf(sqi + sq[j] - 2.f * g, 1e-12f));
        bool same = (tgt[j] == ti);
        dloc[m] = d; sloc[m] = same;
        float cp = same ? d : -1e30f;
        float cn = same ? 1e30f : d;
        if (cp > pv || (cp == pv && j < pj)) { pv = cp; pj = j; }
        if (cn < nv || (cn == nv && j < nj)) { nv = cn; nj = j; }
    }
    for (int off = 32; off; off >>= 1) {
        float opv = __shfl_down(pv, off, 64); int opj = __shfl_down(pj, off, 64);
        float onv = __shfl_down(nv, off, 64); int onj = __shfl_down(nj, off, 64);
        if (opv > pv || (opv == pv && opj < pj)) { pv = opv; pj = opj; }
        if (onv < nv || (onv == nv && onj < nj)) { nv = onv; nj = onj; }
    }
    __shared__ float spv[4], snv[4];
    __shared__ int spj[4], snj[4];
    __shared__ float bb[2];
    __shared__ int cc[2];
    if ((tid & 63) == 0) { int wv = tid >> 6; spv[wv] = pv; spj[wv] = pj; snv[wv] = nv; snj[wv] = nj; }
    __syncthreads();
    if (tid == 0) {
        for (int wv = 1; wv < 4; ++wv) {
            if (spv[wv] > pv || (spv[wv] == pv && spj[wv] < pj)) { pv = spv[wv]; pj = spj[wv]; }
            if (snv[wv] < nv || (snv[wv] == nv && snj[wv] < nj)) { nv = snv[wv]; nj = snj[wv]; }
        }
        hp[i] = pj; hn[i] = nj;
        dsq[i] = sqi; dsq[NSAMP + i] = sqi;   // ||A||^2 init for k_dc
        bestd[i] = pv; bestd[NSAMP + i] = nv;
        bb[0] = pv; bb[1] = nv;
        cc[0] = 0; cc[1] = 0;
    }
    __syncthreads();
    float bp = bb[0], bn = bb[1];
    int lp = 0, ln = 0;
    #pragma unroll
    for (int m = 0; m < 4; ++m) {
        if (sloc[m] && dloc[m] >= bp - MARG) lp++;
        if (!sloc[m] && dloc[m] <= bn + MARG) ln++;
    }
    if (lp) atomicAdd(&cc[0], lp);
    if (ln) atomicAdd(&cc[1], ln);
    __syncthreads();
    if (tid == 0) {
        if (cc[0] > 1) { int k = atomicAdd(cnt, 1); if (k < LISTCAP) list[k] = i; }
        if (cc[1] > 1) { int k = atomicAdd(cnt, 1); if (k < LISTCAP) list[k] = i | (1 << 16); }
    }
}

// ---------------- kernel 3b: exact re-rank of ambiguous rows ----------------
// corr = hi_i.lo_j + lo_i.hi_j recomputed in fp32 (lo = x - hi on the fly).
__global__ __launch_bounds__(256) void k_fix(const float* __restrict__ G,
                                             const float* __restrict__ sq,
                                             const int* __restrict__ tgt,
                                             const float* __restrict__ x,
                                             const ushort_t* __restrict__ xhi,
                                             const float* __restrict__ bestd,
                                             const int* __restrict__ list,
                                             const int* __restrict__ cnt,
                                             int* __restrict__ hp, int* __restrict__ hn) {
    int n = cnt[0]; if (n > LISTCAP) n = LISTCAP;
    int tid = threadIdx.x;
    __shared__ int cand[32];
    __shared__ int ncand;
    __shared__ float bred[4];
    for (int e = blockIdx.x; e < n; e += gridDim.x) {
        int ent = list[e];
        int i = ent & 0xffff, type = ent >> 16;
        if (tid == 0) ncand = 0;
        __syncthreads();
        float bd = bestd[type * NSAMP + i];
        float sqi = sq[i];
        int ti = tgt[i];
        #pragma unroll
        for (int m = 0; m < 4; ++m) {
            int j = tid + 256 * m;
            float g = G[(size_t)i * NSAMP + j];
            float d = sqrtf(fmaxf(sqi + sq[j] - 2.f * g, 1e-12f));
            bool same = (tgt[j] == ti);
            bool fl = (type == 0) ? (same && d >= bd - MARG)
                                  : (!same && d <= bd + MARG);
            if (fl) { int k = atomicAdd(&ncand, 1); if (k < 32) cand[k] = j; }
        }
        __syncthreads();
        int nc = ncand < 32 ? ncand : 32;
        float bestv = (type == 0) ? -3.0e38f : 3.0e38f;
        int bestj = 0x7FFFFFFF;
        const float* xi = x + (size_t)i * D;
        const ushort_t* hi = xhi + (size_t)i * D;
        for (int c = 0; c < nc; ++c) {
            int j = cand[c];
            const float* xj = x + (size_t)j * D;
            const ushort_t* hj = xhi + (size_t)j * D;
            float corr = 0.f;
            #pragma unroll
            for (int m = 0; m < 16; ++m) {
                int k = m * 1024 + tid * 4;
                float4 xa = *(const float4*)(xi + k);
                float4 xb = *(const float4*)(xj + k);
                ushort4 ha = *(const ushort4*)(hi + k);
                ushort4 hb = *(const ushort4*)(hj + k);
                float a0 = bf2f(ha.x), a1 = bf2f(ha.y), a2 = bf2f(ha.z), a3 = bf2f(ha.w);
                float b0 = bf2f(hb.x), b1 = bf2f(hb.y), b2 = bf2f(hb.z), b3 = bf2f(hb.w);
                corr += a0 * (xb.x - b0) + (xa.x - a0) * b0;
                corr += a1 * (xb.y - b1) + (xa.y - a1) * b1;
                corr += a2 * (xb.z - b2) + (xa.z - a2) * b2;
                corr += a3 * (xb.w - b3) + (xa.w - a3) * b3;
            }
            for (int off = 32; off; off >>= 1) corr += __shfl_down(corr, off, 64);
            if ((tid & 63) == 0) bred[tid >> 6] = corr;
            __syncthreads();
            float cs = bred[0] + bred[1] + bred[2] + bred[3];
            float g = G[(size_t)i * NSAMP + j];
            float d2 = sqi + sq[j] - 2.f * (g + cs);
            float d = sqrtf(fmaxf(d2, 1e-12f));
            if (type == 0) {
                if (d > bestv || (d == bestv && j < bestj)) { bestv = d; bestj = j; }
            } else {
                if (d < bestv || (d == bestv && j < bestj)) { bestv = d; bestj = j; }
            }
            __syncthreads();
        }
        if (tid == 0 && nc > 0) { if (type == 0) hp[i] = bestj; else hn[i] = bestj; }
        __syncthreads();
    }
}

// ---------------- kernel 4: DC align via MFMA (R9, unchanged) ----------------
__global__ __launch_bounds__(256) void k_dc_mfma(const ushort_t* __restrict__ xhi,
                                                 const int* __restrict__ hp,
                                                 const int* __restrict__ hn,
                                                 float* __restrict__ dsq) {
    int b = blockIdx.x;
    int which = blockIdx.y;
    int q = blockIdx.z;
    int oidx = (which == 0) ? hp[b] : hn[b];
    const ushort_t* Ag = xhi + (size_t)b * D;
    const ushort_t* Og = xhi + (size_t)oidx * D;

    __shared__ __align__(16) char smem[32768];   // O, then Ot in place

    int tid = threadIdx.x;
    int wv = tid >> 6, lane = tid & 63;
    int quad = lane >> 4, m16 = lane & 15;
    int rt = q * 4 + wv;

    bf16x8 af[4];
    #pragma unroll
    for (int ks = 0; ks < 4; ++ks)
        af[ks] = *(const bf16x8*)(Ag + (rt * 16 + m16) * WH + ks * 32 + quad * 8);

    {
        uint4 stg[8];
        #pragma unroll
        for (int k = 0; k < 8; ++k)
            stg[k] = *(const uint4*)((const char*)Og + (size_t)(tid + 256 * k) * 16);
        #pragma unroll
        for (int k = 0; k < 8; ++k) {
            int g = tid + 256 * k;
            *(uint4*)(smem + lds_off(g >> 4, (g & 15) * 8)) = stg[k];
        }
    }
    __syncthreads();   // B1: O staged

    f32x4 acc[8];
    #pragma unroll
    for (int ti = 0; ti < 8; ++ti)
        acc[ti] = (f32x4){0.f, 0.f, 0.f, 0.f};
    #pragma unroll
    for (int ks = 0; ks < 4; ++ks) {
        bf16x8 of[8];
        #pragma unroll
        for (int ti = 0; ti < 8; ++ti)
            of[ti] = *(const bf16x8*)(smem + lds_off(ti * 16 + m16, (ks * 4 + quad) * 8));
        #pragma unroll
        for (int ti = 0; ti < 8; ++ti)
            acc[ti] = __builtin_amdgcn_mfma_f32_16x16x32_bf16(of[ti], af[ks], acc[ti], 0, 0, 0);
    }

    int c0 = (tid & 31) * 4, h0 = (tid >> 5) * 16;
    uint4 trd[4][2];
    #pragma unroll
    for (int j = 0; j < 4; ++j)
        #pragma unroll
        for (int k = 0; k < 2; ++k)
            trd[j][k] = *(const uint4*)(smem + lds_off(c0 + j, h0 + 8 * k));
    __syncthreads();   // B2: all O reads done

    #pragma unroll
    for (int i = 0; i < 16; ++i) {
        uint v[4];
        #pragma unroll
        for (int j = 0; j < 4; ++j) {
            uint wo = ((const uint*)&trd[j][i >> 3])[(i >> 1) & 3];
            v[j] = (i & 1) ? (wo >> 16) : (wo & 0xffffu);
        }
        uint2 pk;
        pk.x = v[0] | (v[1] << 16);
        pk.y = v[2] | (v[3] << 16);
        *(uint2*)(smem + lds_off(h0 + i, c0)) = pk;
    }

    float tpart = 0.f;
    bf16x8 pf[4];
    {
        float mx = -3.0e38f;
        #pragma unroll
        for (int ti = 0; ti < 8; ++ti)
            #pragma unroll
            for (int r = 0; r < 4; ++r) {
                float s = acc[ti][r] * SCALE;
                acc[ti][r] = s;
                mx = fmaxf(mx, s);
            }
        mx = fmaxf(mx, __shfl_xor(mx, 16, 64));
        mx = fmaxf(mx, __shfl_xor(mx, 32, 64));
        float sum = 0.f, tnum = 0.f;
        #pragma unroll
        for (int ti = 0; ti < 8; ++ti)
            #pragma unroll
            for (int r = 0; r < 4; ++r) {
                float s = acc[ti][r];
                float e = __expf(s - mx);
                acc[ti][r] = e;
                sum += e;
                tnum += s * e;
            }
        sum += __shfl_xor(sum, 16, 64);
        sum += __shfl_xor(sum, 32, 64);
        tnum += __shfl_xor(tnum, 16, 64);
        tnum += __shfl_xor(tnum, 32, 64);
        float inv = 1.f / sum;
        tpart = 0.25f * tnum * inv;

        uint Ep[8][2];
        #pragma unroll
        for (int ti = 0; ti < 8; ++ti) {
            Ep[ti][0] = (uint)f2bf(acc[ti][0] * inv) |
                        ((uint)f2bf(acc[ti][1] * inv) << 16);
            Ep[ti][1] = (uint)f2bf(acc[ti][2] * inv) |
                        ((uint)f2bf(acc[ti][3] * inv) << 16);
        }
        int tih = quad >> 1;
        #pragma unroll
        for (int ks = 0; ks < 4; ++ks) {
            union { uint u[4]; bf16x8 v; } fr;
            #pragma unroll
            for (int k = 0; k < 4; ++k) {
                int src = (((quad << 1) + (k >> 1)) & 3) * 16 + m16;
                int a = __shfl((int)Ep[2 * ks + 0][k & 1], src, 64);
                int bsh = __shfl((int)Ep[2 * ks + 1][k & 1], src, 64);
                fr.u[k] = (uint)((tih == 0) ? a : bsh);
            }
            pf[ks] = fr.v;
        }
    }
    __syncthreads();   // B3: Ot complete

    #pragma unroll
    for (int tj = 0; tj < 8; ++tj)
        acc[tj] = (f32x4){0.f, 0.f, 0.f, 0.f};
    #pragma unroll
    for (int ks = 0; ks < 4; ++ks) {
        bf16x8 otf[8];
        #pragma unroll
        for (int tj = 0; tj < 8; ++tj)
            otf[tj] = *(const bf16x8*)(smem + lds_off(tj * 16 + m16, (ks * 4 + quad) * 8));
        #pragma unroll
        for (int tj = 0; tj < 8; ++tj)
            acc[tj] = __builtin_amdgcn_mfma_f32_16x16x32_bf16(pf[ks], otf[tj], acc[tj], 0, 0, 0);
    }

    float m2 = 0.f;
    #pragma unroll
    for (int tj = 0; tj < 8; ++tj)
        #pragma unroll
        for (int r = 0; r < 4; ++r) {
            float mvv = acc[tj][r];
            m2 += mvv * mvv;
        }
    float part = m2 - 2.f * RSCALE * tpart;
    for (int off = 32; off; off >>= 1) part += __shfl_down(part, off, 64);
    if (lane == 0) atomicAdd(&dsq[which * NSAMP + b], part);
}

// ---------------- kernel 5: final loss ----------------
__global__ void k_loss(const float* __restrict__ dsq, float* __restrict__ out) {
    int tid = threadIdx.x;
    float s = 0.f;
    #pragma unroll
    for (int m = 0; m < 4; ++m) {
        int b = tid + 256 * m;
        float ap = sqrtf(fmaxf(dsq[b], 0.f));
        float an = sqrtf(fmaxf(dsq[NSAMP + b], 0.f));
        s += fmaxf(ap - an + MARGIN, 0.f);
    }
    for (int off = 32; off; off >>= 1) s += __shfl_down(s, off, 64);
    __shared__ float red[4];
    if ((tid & 63) == 0) red[tid >> 6] = s;
    __syncthreads();
    if (tid == 0) out[0] = (red[0] + red[1] + red[2] + red[3]) * (1.f / NSAMP);
}

extern "C" void kernel_launch(void* const* d_in, const int* in_sizes, int n_in,
                              void* d_out, int out_size, void* d_ws, size_t ws_size,
                              hipStream_t stream) {
    const float* x = (const float*)d_in[0];
    const int* tgt = (const int*)d_in[1];
    float* out = (float*)d_out;
    char* ws = (char*)d_ws;

    const size_t XB = (size_t)NSAMP * D * 2;      // 32 MB (xhi)
    const size_t GB1 = (size_t)NSAMP * NSAMP * 4; // 4 MB per G slice
    // KS=16 needs 64+32+4 MB + tail; R7 proved ws >= ~102 MB. Fallback KS=8.
    int nks = (ws_size >= 16 * GB1 + XB + GB1 + (size_t)65536) ? 16 : 8;

    float* Gp = (float*)ws;                               // nks * 4 MB
    ushort_t* xhi = (ushort_t*)(ws + nks * GB1);          // 32 MB
    float* G = (float*)(ws + nks * GB1 + XB);             // 4 MB
    char* tail = ws + nks * GB1 + XB + GB1;
    float* sq = (float*)tail;                             // 4 KB
    float* dsq = sq + NSAMP;                              // 8 KB
    float* bestd = dsq + 2 * NSAMP;                       // 8 KB
    int* hp = (int*)(bestd + 2 * NSAMP);                  // 4 KB
    int* hn = hp + NSAMP;                                 // 4 KB
    int* list = hn + NSAMP;                               // 8 KB
    int* cnt = list + LISTCAP;                            // 64 B

    k_norms_hi<<<NSAMP, 256, 0, stream>>>(x, sq, xhi);
    k_gram_hi<<<dim3(nks, 8, 8), 256, 0, stream>>>(xhi, Gp, D / nks);
    k_fold<<<NSAMP, 256, 0, stream>>>(Gp, G, nks, cnt);
    k_select_flag<<<NSAMP, 256, 0, stream>>>(G, sq, tgt, hp, hn, dsq, bestd, list, cnt);
    k_fix<<<64, 256, 0, stream>>>(G, sq, tgt, x, xhi, bestd, list, cnt, hp, hn);
    k_dc_mfma<<<dim3(NSAMP, 2, 2), 256, 0, stream>>>(xhi, hp, hn, dsq);
    k_loss<<<1, 256, 0, stream>>>(dsq, out);
}